// Round 6
// baseline (127.694 us; speedup 1.0000x reference)
//
#include <hip/hip_runtime.h>

#define Bn 16
#define Hn 128
#define Wn 8192
#define NMAX 64

typedef float nt_f4 __attribute__((ext_vector_type(4)));  // native vec for nontemporal builtin

// =====================================================================
// xi_new (written as float32 into out chunk 1). 16 blocks x 64 threads.
// =====================================================================
__global__ void xi_new_kernel(const int* __restrict__ xi,
                              const int* __restrict__ N,
                              float* __restrict__ out_xi) {
    int b = blockIdx.x;
    int i = threadIdx.x;
    int nb = N[b];
    int s0 = xi[(b * NMAX + i) * 2 + 0];
    int s1 = xi[(b * NMAX + i) * 2 + 1];
    int w = s1 - s0; if (w < 0) w = 0;
    bool valid = i < nb;
    int wv = valid ? w : 0;
    int c = wv;
    #pragma unroll
    for (int d = 1; d < 64; d <<= 1) {
        int t = __shfl_up(c, d, 64);
        if (i >= d) c += t;
    }
    out_xi[(b * NMAX + i) * 2 + 0] = valid ? (float)(c - wv + i) : 0.0f;
    out_xi[(b * NMAX + i) * 2 + 1] = valid ? (float)(c + i) : 0.0f;
}

// =====================================================================
// Segment-oriented row compaction. One block per row (2048 blocks,
// 256 threads = 4 waves).
//  - wave 0 lanes redo the 64-lane width scan (xi is L2-resident)
//  - wave k copies segments k, k+4, ... : src and dst both contiguous
//    -> pure coalesced copy, no code map, no searches, no gathers.
//    lane w writes the sep token (if not last segment).
//  - tail [packed_end, W) zeroed with nontemporal float4 stores.
// Reads ONLY used x columns (~24 MB vs 64 MB full-row staging).
// =====================================================================
__global__ __launch_bounds__(256) void row_copy_kernel(
    const float* __restrict__ x, const int* __restrict__ xi,
    const int* __restrict__ N, const float* __restrict__ sep_param,
    float* __restrict__ out) {
    __shared__ int s_start[NMAX];
    __shared__ int s_w[NMAX];
    __shared__ int s_src0[NMAX];
    __shared__ int s_n, s_tail;

    const int row = blockIdx.x;          // b*H + h  (C==1)
    const int b   = row >> 7;
    const int tid = threadIdx.x;

    if (tid < NMAX) {
        int nb = N[b];
        int s0 = xi[(b * NMAX + tid) * 2 + 0];
        int s1 = xi[(b * NMAX + tid) * 2 + 1];
        int w = s1 - s0; if (w < 0) w = 0;
        bool valid = tid < nb;
        int wv = valid ? w : 0;
        int c = wv;
        #pragma unroll
        for (int d = 1; d < 64; d <<= 1) {
            int t = __shfl_up(c, d, 64);
            if (tid >= d) c += t;
        }
        int start_new = c - wv + tid;    // compressed start
        int end_new   = c + tid;         // compressed end
        s_start[tid] = start_new;
        s_w[tid]     = wv;
        s_src0[tid]  = s0;
        if (tid == 0) s_n = nb;
        // single-writer for s_tail (nb>=1 in practice; guard nb==0)
        int last = (nb > 0) ? (nb - 1) : 0;
        if (tid == last) s_tail = (nb > 0) ? end_new : 0;
    }
    __syncthreads();

    const int nb   = s_n;
    const int tail = s_tail;
    const float sep = sep_param[0];
    const float* __restrict__ xrow = x + (size_t)row * Wn;
    float* __restrict__ orow = out + (size_t)row * Wn;
    const int wave = tid >> 6;
    const int lane = tid & 63;

    // ---- contiguous segment copies (4 waves round-robin) ----
    for (int seg = wave; seg < nb; seg += 4) {
        const int s    = s_start[seg];
        const int w    = s_w[seg];
        const int src0 = s_src0[seg];
        const int wtot = w + (seg < nb - 1 ? 1 : 0);   // +1 for sep slot
        for (int l = lane; l < wtot; l += 64) {
            float v = (l < w) ? xrow[src0 + l] : sep;
            orow[s + l] = v;
        }
    }

    // ---- zero tail [tail, Wn): scalar up to 16B alignment, then f4 NT ----
    const int t4 = (tail + 3) & ~3;
    if (tid < (t4 - tail)) orow[tail + tid] = 0.0f;    // <=3 threads
    const nt_f4 z = {0.0f, 0.0f, 0.0f, 0.0f};
    nt_f4* orow4 = reinterpret_cast<nt_f4*>(orow);
    for (int i4 = (t4 >> 2) + tid; i4 < (Wn >> 2); i4 += 256) {
        __builtin_nontemporal_store(z, orow4 + i4);
    }
}

extern "C" void kernel_launch(void* const* d_in, const int* in_sizes, int n_in,
                              void* d_out, int out_size, void* d_ws, size_t ws_size,
                              hipStream_t stream) {
    const float* x   = (const float*)d_in[0];
    const int* xi    = (const int*)d_in[1];
    const int* N     = (const int*)d_in[2];
    const float* sep = (const float*)d_in[3];

    float* out_x  = (float*)d_out;
    float* out_xi = (float*)d_out + (size_t)Bn * Hn * Wn;

    xi_new_kernel<<<Bn, NMAX, 0, stream>>>(xi, N, out_xi);
    row_copy_kernel<<<Bn * Hn, 256, 0, stream>>>(x, xi, N, sep, out_x);
}

// Round 7
// 119.196 us; speedup vs baseline: 1.0713x; 1.0713x over previous
//
#include <hip/hip_runtime.h>

#define Bn 16
#define Hn 128
#define Wn 8192
#define NMAX 64

typedef float nt_f4 __attribute__((ext_vector_type(4)));  // native vec for nontemporal builtin

// =====================================================================
// xi_new (written as float32 into out chunk 1). 16 blocks x 64 threads.
// =====================================================================
__global__ void xi_new_kernel(const int* __restrict__ xi,
                              const int* __restrict__ N,
                              float* __restrict__ out_xi) {
    int b = blockIdx.x;
    int i = threadIdx.x;
    int nb = N[b];
    int s0 = xi[(b * NMAX + i) * 2 + 0];
    int s1 = xi[(b * NMAX + i) * 2 + 1];
    int w = s1 - s0; if (w < 0) w = 0;
    bool valid = i < nb;
    int wv = valid ? w : 0;
    int c = wv;
    #pragma unroll
    for (int d = 1; d < 64; d <<= 1) {
        int t = __shfl_up(c, d, 64);
        if (i >= d) c += t;
    }
    out_xi[(b * NMAX + i) * 2 + 0] = valid ? (float)(c - wv + i) : 0.0f;
    out_xi[(b * NMAX + i) * 2 + 1] = valid ? (float)(c + i) : 0.0f;
}

// =====================================================================
// Segment-oriented row compaction, MLP-restructured. One block per row
// (2048 blocks, 4 waves). Wave k owns segments k, k+4, ... (<=16).
// Each segment is <=2 predicated 64-lane slots (widths <= 87 + sep).
// PASS 1 issues all 32 independent loads into registers; PASS 2 issues
// all stores. No load->store serialization (R6's failure mode: 1
// outstanding load/wave). Reads only used columns (~24 MB vs 64 MB).
// =====================================================================
__global__ __launch_bounds__(256) void row_pack_kernel(
    const float* __restrict__ x, const int* __restrict__ xi,
    const int* __restrict__ N, const float* __restrict__ sep_param,
    float* __restrict__ out) {
    __shared__ int s_start[NMAX];
    __shared__ int s_w[NMAX];
    __shared__ int s_src0[NMAX];
    __shared__ int s_n, s_tail, s_wide;

    const int row = blockIdx.x;          // b*H + h  (C==1)
    const int b   = row >> 7;
    const int tid = threadIdx.x;

    if (tid < NMAX) {                    // wave 0: 64-lane width scan
        int nb = N[b];
        int s0 = xi[(b * NMAX + tid) * 2 + 0];
        int s1 = xi[(b * NMAX + tid) * 2 + 1];
        int w = s1 - s0; if (w < 0) w = 0;
        bool valid = tid < nb;
        int wv = valid ? w : 0;
        int c = wv;
        #pragma unroll
        for (int d = 1; d < 64; d <<= 1) {
            int t = __shfl_up(c, d, 64);
            if (tid >= d) c += t;
        }
        int start_new = c - wv + tid;
        int end_new   = c + tid;
        s_start[tid] = start_new;
        s_w[tid]     = wv;
        s_src0[tid]  = s0;
        unsigned long long wide = __ballot(wv > 127);
        if (tid == 0) {
            s_n = nb;
            s_wide = (wide != 0ULL) ? 1 : 0;
        }
        int last = (nb > 0) ? (nb - 1) : 0;
        if (tid == last) s_tail = (nb > 0) ? end_new : 0;
    }
    __syncthreads();

    const int nb   = s_n;
    const int tail = s_tail;
    const float sep = sep_param[0];
    const float* __restrict__ xrow = x + (size_t)row * Wn;
    float* __restrict__ orow = out + (size_t)row * Wn;
    const int wave = tid >> 6;
    const int lane = tid & 63;

    // ---- PASS 1: issue ALL loads (independent, predicated) ----
    float v0[16], v1[16];
    int sg_s[16], sg_wt[16];
    #pragma unroll
    for (int k = 0; k < 16; ++k) {
        const int seg = wave + 4 * k;
        const bool act = seg < nb;
        const int s    = act ? s_start[seg] : 0;
        const int w    = act ? s_w[seg] : 0;
        const int src0 = act ? s_src0[seg] : 0;
        sg_s[k]  = s;
        sg_wt[k] = act ? (w + ((seg < nb - 1) ? 1 : 0)) : 0;
        v0[k] = (lane < w)      ? xrow[src0 + lane]      : sep;
        v1[k] = (lane + 64 < w) ? xrow[src0 + lane + 64] : sep;
    }

    // ---- PASS 2: issue ALL stores ----
    #pragma unroll
    for (int k = 0; k < 16; ++k) {
        if (lane < sg_wt[k])      orow[sg_s[k] + lane]      = v0[k];
        if (lane + 64 < sg_wt[k]) orow[sg_s[k] + lane + 64] = v1[k];
    }

    // ---- rare fallback for segments wider than 128 (never in practice) ----
    if (s_wide) {
        for (int seg = wave; seg < nb; seg += 4) {
            const int w = s_w[seg];
            const int wtot = w + ((seg < nb - 1) ? 1 : 0);
            for (int l = 128 + lane; l < wtot; l += 64) {
                orow[s_start[seg] + l] = (l < w) ? xrow[s_src0[seg] + l] : sep;
            }
        }
    }

    // ---- zero tail [tail, Wn): scalar to 16B alignment, then f4 NT ----
    const int t4 = (tail + 3) & ~3;
    if (tid < (t4 - tail)) orow[tail + tid] = 0.0f;    // <=3 threads
    const nt_f4 z = {0.0f, 0.0f, 0.0f, 0.0f};
    nt_f4* orow4 = reinterpret_cast<nt_f4*>(orow);
    for (int i4 = (t4 >> 2) + tid; i4 < (Wn >> 2); i4 += 256) {
        __builtin_nontemporal_store(z, orow4 + i4);
    }
}

extern "C" void kernel_launch(void* const* d_in, const int* in_sizes, int n_in,
                              void* d_out, int out_size, void* d_ws, size_t ws_size,
                              hipStream_t stream) {
    const float* x   = (const float*)d_in[0];
    const int* xi    = (const int*)d_in[1];
    const int* N     = (const int*)d_in[2];
    const float* sep = (const float*)d_in[3];

    float* out_x  = (float*)d_out;
    float* out_xi = (float*)d_out + (size_t)Bn * Hn * Wn;

    xi_new_kernel<<<Bn, NMAX, 0, stream>>>(xi, N, out_xi);
    row_pack_kernel<<<Bn * Hn, 256, 0, stream>>>(x, xi, N, sep, out_x);
}

// Round 8
// 115.377 us; speedup vs baseline: 1.1068x; 1.0331x over previous
//
#include <hip/hip_runtime.h>

#define Bn 16
#define Hn 128
#define Wn 8192
#define NMAX 64

typedef float nt_f4 __attribute__((ext_vector_type(4)));  // native vec for nontemporal builtin

// =====================================================================
// Fused row compaction, LDS-packed. One block per row (2048 blocks,
// 256 threads = 4 waves).
//  - wave 0: 64-lane width scan; blocks with (row&127)==0 also emit
//    xi_new (as float32) -> no separate xi kernel.
//  - PASS 1: all 32 predicated global loads per thread into registers
//    (full MLP, reads ONLY used columns ~25 MB).
//  - PASS 2: scatter into LDS row image (64-lane contiguous runs ->
//    2-way bank aliasing, free) + sep tokens; zero LDS tail.
//  - FINAL: 8 aligned nontemporal float4 stores/thread (store-issue
//    optimal, R7's 37 global store instrs -> 8).
// =====================================================================
__global__ __launch_bounds__(256) void row_pack_lds_kernel(
    const float* __restrict__ x, const int* __restrict__ xi,
    const int* __restrict__ N, const float* __restrict__ sep_param,
    float* __restrict__ out, float* __restrict__ out_xi) {
    __shared__ float s_row[Wn];          // 32 KB row image
    __shared__ int s_start[NMAX];
    __shared__ int s_w[NMAX];
    __shared__ int s_src0[NMAX];
    __shared__ int s_n, s_tail, s_wide;

    const int row = blockIdx.x;          // b*H + h  (C==1)
    const int b   = row >> 7;
    const int tid = threadIdx.x;

    if (tid < NMAX) {                    // wave 0: 64-lane width scan
        int nb = N[b];
        int s0 = xi[(b * NMAX + tid) * 2 + 0];
        int s1 = xi[(b * NMAX + tid) * 2 + 1];
        int w = s1 - s0; if (w < 0) w = 0;
        bool valid = tid < nb;
        int wv = valid ? w : 0;
        int c = wv;
        #pragma unroll
        for (int d = 1; d < 64; d <<= 1) {
            int t = __shfl_up(c, d, 64);
            if (tid >= d) c += t;
        }
        int start_new = c - wv + tid;
        int end_new   = c + tid;
        s_start[tid] = start_new;
        s_w[tid]     = wv;
        s_src0[tid]  = s0;
        unsigned long long wide = __ballot(wv > 127);
        if (tid == 0) {
            s_n = nb;
            s_wide = (wide != 0ULL) ? 1 : 0;
        }
        int last = (nb > 0) ? (nb - 1) : 0;
        if (tid == last) s_tail = (nb > 0) ? end_new : 0;
        if ((row & 127) == 0) {          // fused xi_new (16 writer blocks)
            out_xi[(b * NMAX + tid) * 2 + 0] = valid ? (float)start_new : 0.0f;
            out_xi[(b * NMAX + tid) * 2 + 1] = valid ? (float)end_new : 0.0f;
        }
    }
    __syncthreads();

    const int nb   = s_n;
    const int tail = s_tail;
    const float sep = sep_param[0];
    const float* __restrict__ xrow = x + (size_t)row * Wn;
    float* __restrict__ orow = out + (size_t)row * Wn;
    const int wave = tid >> 6;
    const int lane = tid & 63;

    // ---- PASS 1: issue ALL global loads (independent, predicated) ----
    float v0[16], v1[16];
    int sg_s[16], sg_wt[16];
    #pragma unroll
    for (int k = 0; k < 16; ++k) {
        const int seg = wave + 4 * k;
        const bool act = seg < nb;
        const int s    = act ? s_start[seg] : 0;
        const int w    = act ? s_w[seg] : 0;
        const int src0 = act ? s_src0[seg] : 0;
        sg_s[k]  = s;
        sg_wt[k] = act ? (w + ((seg < nb - 1) ? 1 : 0)) : 0;
        v0[k] = (lane < w)      ? xrow[src0 + lane]      : sep;
        v1[k] = (lane + 64 < w) ? xrow[src0 + lane + 64] : sep;
    }

    // ---- PASS 2: scatter into LDS row image (2-way aliasing = free) ----
    #pragma unroll
    for (int k = 0; k < 16; ++k) {
        if (lane < sg_wt[k])      s_row[sg_s[k] + lane]      = v0[k];
        if (lane + 64 < sg_wt[k]) s_row[sg_s[k] + lane + 64] = v1[k];
    }

    // ---- rare fallback for segments wider than 128 (never in practice) ----
    if (s_wide) {
        for (int seg = wave; seg < nb; seg += 4) {
            const int w = s_w[seg];
            const int wtot = w + ((seg < nb - 1) ? 1 : 0);
            for (int l = 128 + lane; l < wtot; l += 64) {
                s_row[s_start[seg] + l] = (l < w) ? xrow[s_src0[seg] + l] : sep;
            }
        }
    }

    // ---- zero LDS tail [tail, Wn): scalar to 16B alignment, then b128 ----
    const int t4 = (tail + 3) & ~3;
    if (tid < (t4 - tail)) s_row[tail + tid] = 0.0f;    // <=3 threads
    float4* s_row4 = reinterpret_cast<float4*>(s_row);
    const float4 z4 = make_float4(0.0f, 0.0f, 0.0f, 0.0f);
    for (int i4 = (t4 >> 2) + tid; i4 < (Wn >> 2); i4 += 256) {
        s_row4[i4] = z4;
    }
    __syncthreads();

    // ---- FINAL: aligned nontemporal float4 row store ----
    nt_f4* orow4 = reinterpret_cast<nt_f4*>(orow);
    #pragma unroll
    for (int g = 0; g < 8; ++g) {
        float4 t = s_row4[g * 256 + tid];
        nt_f4 v = {t.x, t.y, t.z, t.w};
        __builtin_nontemporal_store(v, orow4 + g * 256 + tid);
    }
}

extern "C" void kernel_launch(void* const* d_in, const int* in_sizes, int n_in,
                              void* d_out, int out_size, void* d_ws, size_t ws_size,
                              hipStream_t stream) {
    const float* x   = (const float*)d_in[0];
    const int* xi    = (const int*)d_in[1];
    const int* N     = (const int*)d_in[2];
    const float* sep = (const float*)d_in[3];

    float* out_x  = (float*)d_out;
    float* out_xi = (float*)d_out + (size_t)Bn * Hn * Wn;

    row_pack_lds_kernel<<<Bn * Hn, 256, 0, stream>>>(x, xi, N, sep, out_x, out_xi);
}